// Round 1
// baseline (764.501 us; speedup 1.0000x reference)
//
#include <hip/hip_runtime.h>
#include <cstdint>

#define IN_C 128
#define HID 32
#define HEADS 4
#define OUT_C 16
#define NGRAPH 128
#define NEG 0.2f

// ---------------- wave-level inclusive scan (int, width 64) ----------------
__device__ __forceinline__ int wave_incl_scan_i(int v) {
  int lane = threadIdx.x & 63;
#pragma unroll
  for (int off = 1; off < 64; off <<= 1) {
    int u = __shfl_up(v, off, 64);
    if (lane >= off) v += u;
  }
  return v;
}

// ---------------- CSR build ----------------
__global__ void k_count(const int* __restrict__ ei, int E, int Etot, int* __restrict__ deg) {
  int e = blockIdx.x * blockDim.x + threadIdx.x;
  if (e >= Etot) return;
  int d = (e < E) ? ei[E + e] : (e - E);   // self-loop tail
  atomicAdd(&deg[d], 1);
}

__global__ void k_scan(const int* __restrict__ deg, int* __restrict__ offs, int n) {
  __shared__ int wsum[16];
  int t = threadIdx.x;
  int lane = t & 63, wid = t >> 6;
  if (t == 0) offs[0] = 0;
  int carry = 0;
  for (int base = 0; base < n; base += 4096) {
    int i0 = base + t * 4;
    int v0 = 0, v1 = 0, v2 = 0, v3 = 0;
    if (i0 + 3 < n) {
      const int4 q = *reinterpret_cast<const int4*>(deg + i0);
      v0 = q.x; v1 = q.y; v2 = q.z; v3 = q.w;
    } else {
      if (i0 < n)     v0 = deg[i0];
      if (i0 + 1 < n) v1 = deg[i0 + 1];
      if (i0 + 2 < n) v2 = deg[i0 + 2];
      if (i0 + 3 < n) v3 = deg[i0 + 3];
    }
    int s = v0 + v1 + v2 + v3;
    int sv = wave_incl_scan_i(s);
    if (lane == 63) wsum[wid] = sv;
    __syncthreads();
    if (wid == 0) {
      int w = (lane < 16) ? wsum[lane] : 0;
      int ws = wave_incl_scan_i(w);
      if (lane < 16) wsum[lane] = ws;
    }
    __syncthreads();
    int prev = (wid > 0 ? wsum[wid - 1] : 0) + carry;
    int total = wsum[15];
    int excl = prev + sv - s;
    if (i0 < n)     offs[i0 + 1] = excl + v0;
    if (i0 + 1 < n) offs[i0 + 2] = excl + v0 + v1;
    if (i0 + 2 < n) offs[i0 + 3] = excl + v0 + v1 + v2;
    if (i0 + 3 < n) offs[i0 + 4] = excl + v0 + v1 + v2 + v3;
    carry += total;
    __syncthreads();
  }
}

__global__ void k_scatter(const int* __restrict__ ei, int E, int Etot,
                          const int* __restrict__ offs, int* __restrict__ cursor,
                          int* __restrict__ ssrc) {
  int e = blockIdx.x * blockDim.x + threadIdx.x;
  if (e >= Etot) return;
  int s, d;
  if (e < E) { s = ei[e]; d = ei[E + e]; } else { s = e - E; d = s; }
  int pos = offs[d] + atomicAdd(&cursor[d], 1);
  ssrc[pos] = s;
}

// ---------------- fp32 register-tiled GEMM: C[M,Nc] = (rowscale.A)[M,K] @ B[K,Nc] ----------------
// BM=64, BK=16, 4x4 per thread. blockDim must be 16*(BN/4).
template <int BN>
__global__ void k_gemm(const float* __restrict__ A, const float* __restrict__ B,
                       const float* __restrict__ rowscale, float* __restrict__ C,
                       int M, int K, int Nc) {
  const int BM = 64, BK = 16;
  __shared__ float As[BK][BM + 4];   // transposed, +4 pad keeps float4 alignment
  __shared__ float Bs[BK][BN];
  const int tid = threadIdx.x;
  const int nth = 16 * (BN / 4);
  const int tx = tid % (BN / 4);
  const int ty = tid / (BN / 4);
  const int row0 = blockIdx.x * BM;
  const int col0 = blockIdx.y * BN;
  float acc[4][4] = {};
  for (int k0 = 0; k0 < K; k0 += BK) {
    for (int idx = tid; idx < BM * BK; idx += nth) {
      int m = idx >> 4, kk = idx & 15;
      int r = row0 + m;
      float v = 0.f;
      if (r < M) {
        v = A[(size_t)r * K + k0 + kk];
        if (rowscale) v *= rowscale[r];
      }
      As[kk][m] = v;
    }
    for (int idx = tid; idx < BK * BN; idx += nth) {
      int kk = idx / BN, c = idx % BN;
      Bs[kk][c] = B[(size_t)(k0 + kk) * Nc + col0 + c];
    }
    __syncthreads();
#pragma unroll
    for (int kk = 0; kk < BK; kk++) {
      float4 a4 = *reinterpret_cast<const float4*>(&As[kk][ty * 4]);
      float4 b4 = *reinterpret_cast<const float4*>(&Bs[kk][tx * 4]);
      float av[4] = {a4.x, a4.y, a4.z, a4.w};
      float bv[4] = {b4.x, b4.y, b4.z, b4.w};
#pragma unroll
      for (int i = 0; i < 4; i++)
#pragma unroll
        for (int j = 0; j < 4; j++)
          acc[i][j] += av[i] * bv[j];
    }
    __syncthreads();
  }
#pragma unroll
  for (int i = 0; i < 4; i++) {
    int r = row0 + ty * 4 + i;
    if (r < M) {
      float4 o = make_float4(acc[i][0], acc[i][1], acc[i][2], acc[i][3]);
      *reinterpret_cast<float4*>(&C[(size_t)r * Nc + col0 + tx * 4]) = o;
    }
  }
}

// ---------------- attention scores: a_src/a_dst[n,h] = <hfeat[n,h,:], att[h,:]> ----------------
template <int H>
__global__ void k_att(const float* __restrict__ hf, const float* __restrict__ att_s,
                      const float* __restrict__ att_d, float* __restrict__ o_s,
                      float* __restrict__ o_d, int N) {
  int t = threadIdx.x;
  int lane32 = t & 31;
  int nl = t >> 5;                 // 8 nodes per 256-block
  int n = blockIdx.x * 8 + nl;
  if (n >= N) return;
  float sa[H], da[H];
#pragma unroll
  for (int h = 0; h < H; h++) {
    float v = hf[(size_t)n * (H * 32) + h * 32 + lane32];
    sa[h] = v * att_s[h * 32 + lane32];
    da[h] = v * att_d[h * 32 + lane32];
  }
#pragma unroll
  for (int off = 16; off > 0; off >>= 1) {
#pragma unroll
    for (int h = 0; h < H; h++) {
      sa[h] += __shfl_xor(sa[h], off, 32);
      da[h] += __shfl_xor(da[h], off, 32);
    }
  }
  if (lane32 == 0) {
#pragma unroll
    for (int h = 0; h < H; h++) { o_s[n * H + h] = sa[h]; o_d[n * H + h] = da[h]; }
  }
}

// ---------------- layer-1 aggregation: wave per dst, 128 channels, fused softmax+ELU ----------------
__global__ void k_aggr1(const int* __restrict__ offs, const int* __restrict__ ssrc,
                        const float* __restrict__ hf, const float* __restrict__ asrc,
                        const float* __restrict__ adst, const float* __restrict__ bias,
                        float* __restrict__ out, int N) {
  int wid = threadIdx.x >> 6;
  int lane = threadIdx.x & 63;
  int d = blockIdx.x * 4 + wid;
  if (d >= N) return;
  int c0 = lane, c1 = lane + 64;
  int h0 = lane >> 5, h1 = h0 + 2;
  float ad0 = adst[d * 4 + h0], ad1 = adst[d * 4 + h1];
  int beg = offs[d], end = offs[d + 1];
  float acc0 = 0.f, acc1 = 0.f, ds0 = 0.f, ds1 = 0.f;
  for (int i = beg; i < end; i++) {
    int s = ssrc[i];                        // wave-uniform -> broadcast
    float e0 = asrc[s * 4 + h0] + ad0; e0 = e0 > 0.f ? e0 : NEG * e0;
    float e1 = asrc[s * 4 + h1] + ad1; e1 = e1 > 0.f ? e1 : NEG * e1;
    float w0 = __expf(e0), w1 = __expf(e1);
    const float* hr = hf + (size_t)s * 128;
    acc0 += w0 * hr[c0];
    acc1 += w1 * hr[c1];
    ds0 += w0; ds1 += w1;
  }
  float r0 = acc0 / ds0 + bias[c0];
  float r1 = acc1 / ds1 + bias[c1];
  out[(size_t)d * 128 + c0] = r0 > 0.f ? r0 : expm1f(r0);
  out[(size_t)d * 128 + c1] = r1 > 0.f ? r1 : expm1f(r1);
}

// ---------------- layer-2 aggregation: 32-lane group per dst, 32 channels ----------------
__global__ void k_aggr2(const int* __restrict__ offs, const int* __restrict__ ssrc,
                        const float* __restrict__ hf, const float* __restrict__ asrc,
                        const float* __restrict__ adst, const float* __restrict__ bias,
                        float* __restrict__ out, int N) {
  int grp = threadIdx.x >> 5;
  int c = threadIdx.x & 31;
  int d = blockIdx.x * 8 + grp;
  if (d >= N) return;
  float ad = adst[d];
  int beg = offs[d], end = offs[d + 1];
  float acc = 0.f, ds = 0.f;
  for (int i = beg; i < end; i++) {
    int s = ssrc[i];
    float e = asrc[s] + ad; e = e > 0.f ? e : NEG * e;
    float w = __expf(e);
    acc += w * hf[(size_t)s * 32 + c];
    ds += w;
  }
  float r = acc / ds + bias[c];
  out[(size_t)d * 32 + c] = r > 0.f ? r : expm1f(r);
}

// ---------------- pool (mean per graph, batch sorted) + FC ----------------
__global__ void k_pool_fc(const float* __restrict__ h2, const int* __restrict__ batch,
                          const float* __restrict__ fcW, const float* __restrict__ fcb,
                          float* __restrict__ out, int N) {
  int g = blockIdx.x;
  int lo = 0, hi = N;
  while (lo < hi) { int mid = (lo + hi) >> 1; if (batch[mid] < g) lo = mid + 1; else hi = mid; }
  int beg = lo;
  hi = N;
  while (lo < hi) { int mid = (lo + hi) >> 1; if (batch[mid] < g + 1) lo = mid + 1; else hi = mid; }
  int end = lo;
  int t = threadIdx.x, c = t & 31, sub = t >> 5;
  float acc = 0.f;
  for (int n = beg + sub; n < end; n += 8) acc += h2[(size_t)n * 32 + c];
  __shared__ float red[8][32];
  __shared__ float pooled[32];
  red[sub][c] = acc;
  __syncthreads();
  if (sub == 0) {
    float s = 0.f;
#pragma unroll
    for (int i = 0; i < 8; i++) s += red[i][c];
    float cnt = (float)(end - beg);
    pooled[c] = s / fmaxf(cnt, 1.f);
  }
  __syncthreads();
  if (t < 16) {
    float r = fcb[t];
#pragma unroll
    for (int cc = 0; cc < 32; cc++) r += pooled[cc] * fcW[cc * 16 + t];
    out[g * 16 + t] = r;
  }
}

// ---------------- host launch ----------------
extern "C" void kernel_launch(void* const* d_in, const int* in_sizes, int n_in,
                              void* d_out, int out_size, void* d_ws, size_t ws_size,
                              hipStream_t stream) {
  const float* x     = (const float*)d_in[0];
  const int*   ei    = (const int*)d_in[1];
  const int*   batch = (const int*)d_in[2];
  const float* nw    = (const float*)d_in[3];
  const float* W1    = (const float*)d_in[4];
  const float* as1w  = (const float*)d_in[5];
  const float* ad1w  = (const float*)d_in[6];
  const float* b1    = (const float*)d_in[7];
  const float* W2    = (const float*)d_in[8];
  const float* as2w  = (const float*)d_in[9];
  const float* ad2w  = (const float*)d_in[10];
  const float* b2    = (const float*)d_in[11];
  const float* fcW   = (const float*)d_in[12];
  const float* fcb   = (const float*)d_in[13];
  float* out = (float*)d_out;

  const int N = in_sizes[0] / IN_C;
  const int E = in_sizes[1] / 2;
  const int Etot = E + N;

  char* w = (char*)d_ws;
  size_t ofs = 0;
  auto alloc = [&](size_t bytes) {
    char* p = w + ofs;
    ofs += (bytes + 255) & ~(size_t)255;
    return p;
  };
  float* hfeat1 = (float*)alloc((size_t)N * 128 * 4);  // also reused for layer-2 buffers
  float* out1   = (float*)alloc((size_t)N * 128 * 4);
  float* asrc1  = (float*)alloc((size_t)N * 4 * 4);
  float* adst1  = (float*)alloc((size_t)N * 4 * 4);
  int*   deg    = (int*)alloc((size_t)N * 4);
  int*   offs   = (int*)alloc((size_t)(N + 1) * 4);
  int*   cursor = (int*)alloc((size_t)N * 4);
  int*   ssrc   = (int*)alloc((size_t)Etot * 4);
  // layer-2 buffers alias the hfeat1 region (hfeat1 dead after k_aggr1)
  float* hfeat2 = hfeat1;                       // N*32
  float* h2     = hfeat1 + (size_t)N * 32;      // N*32
  float* asrc2  = hfeat1 + (size_t)N * 64;      // N
  float* adst2  = hfeat1 + (size_t)N * 64 + N;  // N

  hipMemsetAsync(deg, 0, (size_t)N * 4, stream);
  hipMemsetAsync(cursor, 0, (size_t)N * 4, stream);

  // CSR build (shared by both layers)
  k_count<<<(Etot + 255) / 256, 256, 0, stream>>>(ei, E, Etot, deg);
  k_scan<<<1, 1024, 0, stream>>>(deg, offs, N);
  k_scatter<<<(Etot + 255) / 256, 256, 0, stream>>>(ei, E, Etot, offs, cursor, ssrc);

  // layer 1
  k_gemm<64><<<dim3((N + 63) / 64, 2), 256, 0, stream>>>(x, W1, nw, hfeat1, N, 128, 128);
  k_att<4><<<(N + 7) / 8, 256, 0, stream>>>(hfeat1, as1w, ad1w, asrc1, adst1, N);
  k_aggr1<<<(N + 3) / 4, 256, 0, stream>>>(offs, ssrc, hfeat1, asrc1, adst1, b1, out1, N);

  // layer 2
  k_gemm<32><<<dim3((N + 63) / 64, 1), 128, 0, stream>>>(out1, W2, nullptr, hfeat2, N, 128, 32);
  k_att<1><<<(N + 7) / 8, 256, 0, stream>>>(hfeat2, as2w, ad2w, asrc2, adst2, N);
  k_aggr2<<<(N + 7) / 8, 256, 0, stream>>>(offs, ssrc, hfeat2, asrc2, adst2, b2, h2, N);

  // pool + fc
  k_pool_fc<<<NGRAPH, 256, 0, stream>>>(h2, batch, fcW, fcb, out, N);
}

// Round 2
// 594.474 us; speedup vs baseline: 1.2860x; 1.2860x over previous
//
#include <hip/hip_runtime.h>
#include <cstdint>

#define IN_C 128
#define HID 32
#define HEADS 4
#define OUT_C 16
#define NGRAPH 128
#define NEG 0.2f

typedef unsigned int uint;
typedef unsigned short ushort;

__device__ __forceinline__ ushort f2bf(float f) {
  uint u = __float_as_uint(f);
  uint r = (u + 0x7FFF + ((u >> 16) & 1)) >> 16;   // RNE
  return (ushort)r;
}
__device__ __forceinline__ float bflo(uint p) { return __uint_as_float(p << 16); }
__device__ __forceinline__ float bfhi(uint p) { return __uint_as_float(p & 0xFFFF0000u); }

// ---------------- wave-level inclusive scan (int, width 64) ----------------
__device__ __forceinline__ int wave_incl_scan_i(int v) {
  int lane = threadIdx.x & 63;
#pragma unroll
  for (int off = 1; off < 64; off <<= 1) {
    int u = __shfl_up(v, off, 64);
    if (lane >= off) v += u;
  }
  return v;
}

// ---------------- CSR build ----------------
__global__ void k_count(const int* __restrict__ ei, int E, int Etot, int* __restrict__ deg) {
  int e = blockIdx.x * blockDim.x + threadIdx.x;
  if (e >= Etot) return;
  int d = (e < E) ? ei[E + e] : (e - E);   // self-loop tail
  atomicAdd(&deg[d], 1);
}

__global__ void k_scan(const int* __restrict__ deg, int* __restrict__ offs, int n) {
  __shared__ int wsum[16];
  int t = threadIdx.x;
  int lane = t & 63, wid = t >> 6;
  if (t == 0) offs[0] = 0;
  int carry = 0;
  for (int base = 0; base < n; base += 16384) {
    int i0 = base + t * 16;
    int v[16];
#pragma unroll
    for (int j = 0; j < 16; j += 4) {
      int idx = i0 + j;
      if (idx + 3 < n) {
        const int4 q = *reinterpret_cast<const int4*>(deg + idx);
        v[j] = q.x; v[j + 1] = q.y; v[j + 2] = q.z; v[j + 3] = q.w;
      } else {
        v[j]     = (idx < n)     ? deg[idx]     : 0;
        v[j + 1] = (idx + 1 < n) ? deg[idx + 1] : 0;
        v[j + 2] = (idx + 2 < n) ? deg[idx + 2] : 0;
        v[j + 3] = (idx + 3 < n) ? deg[idx + 3] : 0;
      }
    }
    int s = 0;
#pragma unroll
    for (int j = 0; j < 16; j++) s += v[j];
    int sv = wave_incl_scan_i(s);
    if (lane == 63) wsum[wid] = sv;
    __syncthreads();
    if (wid == 0) {
      int w = (lane < 16) ? wsum[lane] : 0;
      int ws = wave_incl_scan_i(w);
      if (lane < 16) wsum[lane] = ws;
    }
    __syncthreads();
    int run = (wid > 0 ? wsum[wid - 1] : 0) + carry + sv - s;
#pragma unroll
    for (int j = 0; j < 16; j++) {
      run += v[j];
      if (i0 + j < n) offs[i0 + j + 1] = run;
    }
    carry += wsum[15];
    __syncthreads();
  }
}

__global__ void k_scatter(const int* __restrict__ ei, int E, int Etot,
                          const int* __restrict__ offs, int* __restrict__ cursor,
                          int* __restrict__ ssrc) {
  int e = blockIdx.x * blockDim.x + threadIdx.x;
  if (e >= Etot) return;
  int s, d;
  if (e < E) { s = ei[e]; d = ei[E + e]; } else { s = e - E; d = s; }
  int pos = offs[d] + atomicAdd(&cursor[d], 1);
  ssrc[pos] = s;
}

// ---------------- GEMM1: hb1[M,128](bf16) = (nw.x)[M,128] @ W1[128,128] ----------------
// BM=64, BK=16, BN=64 (grid.y=2), 4x4/thread, blockDim 256.
__global__ void k_gemm1(const float* __restrict__ A, const float* __restrict__ B,
                        const float* __restrict__ rowscale, ushort* __restrict__ Cb,
                        int M, int K, int Nc) {
  const int BM = 64, BK = 16, BN = 64;
  __shared__ float As[BK][BM + 4];
  __shared__ float Bs[BK][BN];
  const int tid = threadIdx.x;
  const int nth = 256;
  const int tx = tid % (BN / 4);
  const int ty = tid / (BN / 4);
  const int row0 = blockIdx.x * BM;
  const int col0 = blockIdx.y * BN;
  float acc[4][4] = {};
  for (int k0 = 0; k0 < K; k0 += BK) {
    for (int idx = tid; idx < BM * BK; idx += nth) {
      int m = idx >> 4, kk = idx & 15;
      int r = row0 + m;
      float v = 0.f;
      if (r < M) v = A[(size_t)r * K + k0 + kk] * rowscale[r];
      As[kk][m] = v;
    }
    for (int idx = tid; idx < BK * BN; idx += nth) {
      int kk = idx / BN, c = idx % BN;
      Bs[kk][c] = B[(size_t)(k0 + kk) * Nc + col0 + c];
    }
    __syncthreads();
#pragma unroll
    for (int kk = 0; kk < BK; kk++) {
      float4 a4 = *reinterpret_cast<const float4*>(&As[kk][ty * 4]);
      float4 b4 = *reinterpret_cast<const float4*>(&Bs[kk][tx * 4]);
      float av[4] = {a4.x, a4.y, a4.z, a4.w};
      float bv[4] = {b4.x, b4.y, b4.z, b4.w};
#pragma unroll
      for (int i = 0; i < 4; i++)
#pragma unroll
        for (int j = 0; j < 4; j++)
          acc[i][j] += av[i] * bv[j];
    }
    __syncthreads();
  }
#pragma unroll
  for (int i = 0; i < 4; i++) {
    int r = row0 + ty * 4 + i;
    if (r < M) {
      ushort4 o;
      o.x = f2bf(acc[i][0]); o.y = f2bf(acc[i][1]);
      o.z = f2bf(acc[i][2]); o.w = f2bf(acc[i][3]);
      *reinterpret_cast<ushort4*>(&Cb[(size_t)r * Nc + col0 + tx * 4]) = o;
    }
  }
}

// ---------------- GEMM2: hb2[M,32](bf16) = out1b[M,128](bf16) @ W2[128,32] ----------------
// BM=64, BK=16, BN=32, blockDim 128.
__global__ void k_gemm2(const ushort* __restrict__ A, const float* __restrict__ B,
                        ushort* __restrict__ Cb, int M, int K, int Nc) {
  const int BM = 64, BK = 16, BN = 32;
  __shared__ float As[BK][BM + 4];
  __shared__ float Bs[BK][BN];
  const int tid = threadIdx.x;
  const int nth = 128;
  const int tx = tid % (BN / 4);
  const int ty = tid / (BN / 4);
  const int row0 = blockIdx.x * BM;
  float acc[4][4] = {};
  for (int k0 = 0; k0 < K; k0 += BK) {
    for (int idx = tid; idx < BM * BK / 2; idx += nth) {
      int m = idx >> 3;
      int kp = (idx & 7) * 2;
      int r = row0 + m;
      float v0 = 0.f, v1 = 0.f;
      if (r < M) {
        uint p = *reinterpret_cast<const uint*>(A + (size_t)r * K + k0 + kp);
        v0 = bflo(p); v1 = bfhi(p);
      }
      As[kp][m] = v0; As[kp + 1][m] = v1;
    }
    for (int idx = tid; idx < BK * BN; idx += nth) {
      int kk = idx / BN, c = idx % BN;
      Bs[kk][c] = B[(size_t)(k0 + kk) * Nc + c];
    }
    __syncthreads();
#pragma unroll
    for (int kk = 0; kk < BK; kk++) {
      float4 a4 = *reinterpret_cast<const float4*>(&As[kk][ty * 4]);
      float4 b4 = *reinterpret_cast<const float4*>(&Bs[kk][tx * 4]);
      float av[4] = {a4.x, a4.y, a4.z, a4.w};
      float bv[4] = {b4.x, b4.y, b4.z, b4.w};
#pragma unroll
      for (int i = 0; i < 4; i++)
#pragma unroll
        for (int j = 0; j < 4; j++)
          acc[i][j] += av[i] * bv[j];
    }
    __syncthreads();
  }
#pragma unroll
  for (int i = 0; i < 4; i++) {
    int r = row0 + ty * 4 + i;
    if (r < M) {
      ushort4 o;
      o.x = f2bf(acc[i][0]); o.y = f2bf(acc[i][1]);
      o.z = f2bf(acc[i][2]); o.w = f2bf(acc[i][3]);
      *reinterpret_cast<ushort4*>(&Cb[(size_t)r * Nc + tx * 4]) = o;
    }
  }
}

// ---------------- attention scores layer 1 (bf16 features, wave per node) ----------------
__global__ void k_att1(const ushort* __restrict__ hb, const float* __restrict__ att_s,
                       const float* __restrict__ att_d, float* __restrict__ o_s,
                       float* __restrict__ o_d, int N) {
  int wid = threadIdx.x >> 6, lane = threadIdx.x & 63;
  int n = blockIdx.x * 4 + wid;
  if (n >= N) return;
  int h = lane >> 4;
  int ch = (2 * lane) & 31;
  uint p = *reinterpret_cast<const uint*>(hb + (size_t)n * 128 + 2 * lane);
  float v0 = bflo(p), v1 = bfhi(p);
  float sa = v0 * att_s[h * 32 + ch] + v1 * att_s[h * 32 + ch + 1];
  float da = v0 * att_d[h * 32 + ch] + v1 * att_d[h * 32 + ch + 1];
#pragma unroll
  for (int off = 8; off > 0; off >>= 1) {
    sa += __shfl_xor(sa, off, 16);
    da += __shfl_xor(da, off, 16);
  }
  if ((lane & 15) == 0) { o_s[n * 4 + h] = sa; o_d[n * 4 + h] = da; }
}

// ---------------- attention scores layer 2 (16 lanes per node) ----------------
__global__ void k_att2(const ushort* __restrict__ hb, const float* __restrict__ att_s,
                       const float* __restrict__ att_d, float* __restrict__ o_s,
                       float* __restrict__ o_d, int N) {
  int grp = threadIdx.x >> 4, l = threadIdx.x & 15;
  int n = blockIdx.x * 16 + grp;
  if (n >= N) return;
  uint p = *reinterpret_cast<const uint*>(hb + (size_t)n * 32 + 2 * l);
  float v0 = bflo(p), v1 = bfhi(p);
  float sa = v0 * att_s[2 * l] + v1 * att_s[2 * l + 1];
  float da = v0 * att_d[2 * l] + v1 * att_d[2 * l + 1];
#pragma unroll
  for (int off = 8; off > 0; off >>= 1) {
    sa += __shfl_xor(sa, off, 16);
    da += __shfl_xor(da, off, 16);
  }
  if (l == 0) { o_s[n] = sa; o_d[n] = da; }
}

// ---------------- layer-1 aggregation: wave per dst, bf16x2 gather, 4-edge unroll ----------------
__global__ void k_aggr1(const int* __restrict__ offs, const int* __restrict__ ssrc,
                        const ushort* __restrict__ hb, const float* __restrict__ asrc,
                        const float* __restrict__ adst, const float* __restrict__ bias,
                        ushort* __restrict__ outb, int N) {
  int wid = threadIdx.x >> 6;
  int lane = threadIdx.x & 63;
  int d = blockIdx.x * 4 + wid;
  if (d >= N) return;
  int h = lane >> 4;
  float ad = adst[d * 4 + h];
  int beg = offs[d], end = offs[d + 1];
  float ax = 0.f, ay = 0.f, ds = 0.f;
  int i = beg;
  for (; i + 4 <= end; i += 4) {
    int s0 = ssrc[i], s1 = ssrc[i + 1], s2 = ssrc[i + 2], s3 = ssrc[i + 3];
    uint p0 = *reinterpret_cast<const uint*>(hb + (size_t)s0 * 128 + 2 * lane);
    uint p1 = *reinterpret_cast<const uint*>(hb + (size_t)s1 * 128 + 2 * lane);
    uint p2 = *reinterpret_cast<const uint*>(hb + (size_t)s2 * 128 + 2 * lane);
    uint p3 = *reinterpret_cast<const uint*>(hb + (size_t)s3 * 128 + 2 * lane);
    float e0 = asrc[s0 * 4 + h] + ad; e0 = e0 > 0.f ? e0 : NEG * e0;
    float e1 = asrc[s1 * 4 + h] + ad; e1 = e1 > 0.f ? e1 : NEG * e1;
    float e2 = asrc[s2 * 4 + h] + ad; e2 = e2 > 0.f ? e2 : NEG * e2;
    float e3 = asrc[s3 * 4 + h] + ad; e3 = e3 > 0.f ? e3 : NEG * e3;
    float w0 = __expf(e0), w1 = __expf(e1), w2 = __expf(e2), w3 = __expf(e3);
    ax += w0 * bflo(p0) + w1 * bflo(p1) + w2 * bflo(p2) + w3 * bflo(p3);
    ay += w0 * bfhi(p0) + w1 * bfhi(p1) + w2 * bfhi(p2) + w3 * bfhi(p3);
    ds += w0 + w1 + w2 + w3;
  }
  for (; i < end; i++) {
    int s = ssrc[i];
    uint p = *reinterpret_cast<const uint*>(hb + (size_t)s * 128 + 2 * lane);
    float e = asrc[s * 4 + h] + ad; e = e > 0.f ? e : NEG * e;
    float w = __expf(e);
    ax += w * bflo(p); ay += w * bfhi(p); ds += w;
  }
  float inv = 1.f / ds;
  float rx = ax * inv + bias[2 * lane];
  float ry = ay * inv + bias[2 * lane + 1];
  rx = rx > 0.f ? rx : expm1f(rx);
  ry = ry > 0.f ? ry : expm1f(ry);
  uint pk = (uint)f2bf(rx) | ((uint)f2bf(ry) << 16);
  *reinterpret_cast<uint*>(outb + (size_t)d * 128 + 2 * lane) = pk;
}

// ---------------- layer-2 aggregation: 16 lanes per dst, bf16x2 gather ----------------
__global__ void k_aggr2(const int* __restrict__ offs, const int* __restrict__ ssrc,
                        const ushort* __restrict__ hb, const float* __restrict__ asrc,
                        const float* __restrict__ adst, const float* __restrict__ bias,
                        float* __restrict__ out, int N) {
  int grp = threadIdx.x >> 4;
  int l = threadIdx.x & 15;
  int d = blockIdx.x * 16 + grp;
  if (d >= N) return;
  float ad = adst[d];
  int beg = offs[d], end = offs[d + 1];
  float ax = 0.f, ay = 0.f, ds = 0.f;
  int i = beg;
  for (; i + 4 <= end; i += 4) {
    int s0 = ssrc[i], s1 = ssrc[i + 1], s2 = ssrc[i + 2], s3 = ssrc[i + 3];
    uint p0 = *reinterpret_cast<const uint*>(hb + (size_t)s0 * 32 + 2 * l);
    uint p1 = *reinterpret_cast<const uint*>(hb + (size_t)s1 * 32 + 2 * l);
    uint p2 = *reinterpret_cast<const uint*>(hb + (size_t)s2 * 32 + 2 * l);
    uint p3 = *reinterpret_cast<const uint*>(hb + (size_t)s3 * 32 + 2 * l);
    float e0 = asrc[s0] + ad; e0 = e0 > 0.f ? e0 : NEG * e0;
    float e1 = asrc[s1] + ad; e1 = e1 > 0.f ? e1 : NEG * e1;
    float e2 = asrc[s2] + ad; e2 = e2 > 0.f ? e2 : NEG * e2;
    float e3 = asrc[s3] + ad; e3 = e3 > 0.f ? e3 : NEG * e3;
    float w0 = __expf(e0), w1 = __expf(e1), w2 = __expf(e2), w3 = __expf(e3);
    ax += w0 * bflo(p0) + w1 * bflo(p1) + w2 * bflo(p2) + w3 * bflo(p3);
    ay += w0 * bfhi(p0) + w1 * bfhi(p1) + w2 * bfhi(p2) + w3 * bfhi(p3);
    ds += w0 + w1 + w2 + w3;
  }
  for (; i < end; i++) {
    int s = ssrc[i];
    uint p = *reinterpret_cast<const uint*>(hb + (size_t)s * 32 + 2 * l);
    float e = asrc[s] + ad; e = e > 0.f ? e : NEG * e;
    float w = __expf(e);
    ax += w * bflo(p); ay += w * bfhi(p); ds += w;
  }
  float inv = 1.f / ds;
  float rx = ax * inv + bias[2 * l];
  float ry = ay * inv + bias[2 * l + 1];
  rx = rx > 0.f ? rx : expm1f(rx);
  ry = ry > 0.f ? ry : expm1f(ry);
  float2 o = make_float2(rx, ry);
  *reinterpret_cast<float2*>(&out[(size_t)d * 32 + 2 * l]) = o;
}

// ---------------- pool (mean per graph, batch sorted) + FC ----------------
__global__ void k_pool_fc(const float* __restrict__ h2, const int* __restrict__ batch,
                          const float* __restrict__ fcW, const float* __restrict__ fcb,
                          float* __restrict__ out, int N) {
  int g = blockIdx.x;
  int lo = 0, hi = N;
  while (lo < hi) { int mid = (lo + hi) >> 1; if (batch[mid] < g) lo = mid + 1; else hi = mid; }
  int beg = lo;
  hi = N;
  while (lo < hi) { int mid = (lo + hi) >> 1; if (batch[mid] < g + 1) lo = mid + 1; else hi = mid; }
  int end = lo;
  int t = threadIdx.x, c = t & 31, sub = t >> 5;
  float acc = 0.f;
  for (int n = beg + sub; n < end; n += 8) acc += h2[(size_t)n * 32 + c];
  __shared__ float red[8][32];
  __shared__ float pooled[32];
  red[sub][c] = acc;
  __syncthreads();
  if (sub == 0) {
    float s = 0.f;
#pragma unroll
    for (int i = 0; i < 8; i++) s += red[i][c];
    float cnt = (float)(end - beg);
    pooled[c] = s / fmaxf(cnt, 1.f);
  }
  __syncthreads();
  if (t < 16) {
    float r = fcb[t];
#pragma unroll
    for (int cc = 0; cc < 32; cc++) r += pooled[cc] * fcW[cc * 16 + t];
    out[g * 16 + t] = r;
  }
}

// ---------------- host launch ----------------
extern "C" void kernel_launch(void* const* d_in, const int* in_sizes, int n_in,
                              void* d_out, int out_size, void* d_ws, size_t ws_size,
                              hipStream_t stream) {
  const float* x     = (const float*)d_in[0];
  const int*   ei    = (const int*)d_in[1];
  const int*   batch = (const int*)d_in[2];
  const float* nw    = (const float*)d_in[3];
  const float* W1    = (const float*)d_in[4];
  const float* as1w  = (const float*)d_in[5];
  const float* ad1w  = (const float*)d_in[6];
  const float* b1    = (const float*)d_in[7];
  const float* W2    = (const float*)d_in[8];
  const float* as2w  = (const float*)d_in[9];
  const float* ad2w  = (const float*)d_in[10];
  const float* b2    = (const float*)d_in[11];
  const float* fcW   = (const float*)d_in[12];
  const float* fcb   = (const float*)d_in[13];
  float* out = (float*)d_out;

  const int N = in_sizes[0] / IN_C;
  const int E = in_sizes[1] / 2;
  const int Etot = E + N;

  char* w = (char*)d_ws;
  size_t ofs = 0;
  auto alloc = [&](size_t bytes) {
    char* p = w + ofs;
    ofs += (bytes + 255) & ~(size_t)255;
    return p;
  };
  ushort* hb1    = (ushort*)alloc((size_t)N * 128 * 2);
  ushort* out1b  = (ushort*)alloc((size_t)N * 128 * 2);
  ushort* hb2    = (ushort*)alloc((size_t)N * 32 * 2);
  float*  h2     = (float*)alloc((size_t)N * 32 * 4);
  float*  asrc1  = (float*)alloc((size_t)N * 4 * 4);
  float*  adst1  = (float*)alloc((size_t)N * 4 * 4);
  float*  asrc2  = (float*)alloc((size_t)N * 4);
  float*  adst2  = (float*)alloc((size_t)N * 4);
  int*    deg    = (int*)alloc((size_t)N * 4);
  int*    offs   = (int*)alloc((size_t)(N + 1) * 4);
  int*    cursor = (int*)alloc((size_t)N * 4);
  int*    ssrc   = (int*)alloc((size_t)Etot * 4);

  hipMemsetAsync(deg, 0, (size_t)N * 4, stream);
  hipMemsetAsync(cursor, 0, (size_t)N * 4, stream);

  // CSR build (shared by both layers)
  k_count<<<(Etot + 255) / 256, 256, 0, stream>>>(ei, E, Etot, deg);
  k_scan<<<1, 1024, 0, stream>>>(deg, offs, N);
  k_scatter<<<(Etot + 255) / 256, 256, 0, stream>>>(ei, E, Etot, offs, cursor, ssrc);

  // layer 1
  k_gemm1<<<dim3((N + 63) / 64, 2), 256, 0, stream>>>(x, W1, nw, hb1, N, 128, 128);
  k_att1<<<(N + 3) / 4, 256, 0, stream>>>(hb1, as1w, ad1w, asrc1, adst1, N);
  k_aggr1<<<(N + 3) / 4, 256, 0, stream>>>(offs, ssrc, hb1, asrc1, adst1, b1, out1b, N);

  // layer 2
  k_gemm2<<<dim3((N + 63) / 64, 1), 128, 0, stream>>>(out1b, W2, hb2, N, 128, 32);
  k_att2<<<(N + 15) / 16, 256, 0, stream>>>(hb2, as2w, ad2w, asrc2, adst2, N);
  k_aggr2<<<(N + 15) / 16, 256, 0, stream>>>(offs, ssrc, hb2, asrc2, adst2, b2, h2, N);

  // pool + fc
  k_pool_fc<<<NGRAPH, 256, 0, stream>>>(h2, batch, fcW, fcb, out, N);
}

// Round 3
// 437.791 us; speedup vs baseline: 1.7463x; 1.3579x over previous
//
#include <hip/hip_runtime.h>
#include <cstdint>

#define IN_C 128
#define HID 32
#define HEADS 4
#define OUT_C 16
#define NGRAPH 128
#define NEG 0.2f
#define NB_MAX 256      // buckets of 512 dst nodes; N=100K -> 196 buckets

typedef unsigned int uint;
typedef unsigned short ushort;

__device__ __forceinline__ ushort f2bf(float f) {
  uint u = __float_as_uint(f);
  uint r = (u + 0x7FFF + ((u >> 16) & 1)) >> 16;   // RNE
  return (ushort)r;
}
__device__ __forceinline__ float bflo(uint p) { return __uint_as_float(p << 16); }
__device__ __forceinline__ float bfhi(uint p) { return __uint_as_float(p & 0xFFFF0000u); }

__device__ __forceinline__ int wave_incl_scan_i(int v) {
  int lane = threadIdx.x & 63;
#pragma unroll
  for (int off = 1; off < 64; off <<= 1) {
    int u = __shfl_up(v, off, 64);
    if (lane >= off) v += u;
  }
  return v;
}

// ---------------- binned CSR build ----------------
// bucket = dst >> 9 (512 nodes per bucket)

__global__ void k_bhist(const int* __restrict__ ei, int E, int Etot, int NB,
                        int* __restrict__ bcnt) {
  __shared__ int h[NB_MAX];
  int t = threadIdx.x;
  for (int b = t; b < NB; b += 256) h[b] = 0;
  __syncthreads();
  int base = blockIdx.x * 4096;
  int end = min(base + 4096, Etot);
  for (int e = base + t; e < end; e += 256) {
    int d = (e < E) ? ei[E + e] : (e - E);
    atomicAdd(&h[d >> 9], 1);
  }
  __syncthreads();
  for (int b = t; b < NB; b += 256) if (h[b]) atomicAdd(&bcnt[b], h[b]);
}

__global__ void k_bscan(const int* __restrict__ bcnt, int NB,
                        int* __restrict__ bstart, int Etot,
                        int* __restrict__ offs, int N) {
  if (threadIdx.x == 0) {
    int run = 0;
    for (int b = 0; b < NB; b++) { bstart[b] = run; run += bcnt[b]; }
    bstart[NB] = run;
    offs[N] = Etot;
  }
}

__global__ void k_bin(const int* __restrict__ ei, int E, int Etot, int NB,
                      const int* __restrict__ bstart, int* __restrict__ bcur,
                      uint* __restrict__ bbuf) {
  __shared__ int h[NB_MAX];
  __shared__ int baseo[NB_MAX];
  int t = threadIdx.x;
  for (int b = t; b < NB; b += 256) h[b] = 0;
  __syncthreads();
  int cbase = blockIdx.x * 4096;
  int cend = min(cbase + 4096, Etot);
  for (int e = cbase + t; e < cend; e += 256) {
    int d = (e < E) ? ei[E + e] : (e - E);
    atomicAdd(&h[d >> 9], 1);
  }
  __syncthreads();
  for (int b = t; b < NB; b += 256) {
    int c = h[b];
    baseo[b] = c ? atomicAdd(&bcur[b], c) : 0;
    h[b] = 0;
  }
  __syncthreads();
  for (int e = cbase + t; e < cend; e += 256) {
    int s, d;
    if (e < E) { s = ei[e]; d = ei[E + e]; } else { s = e - E; d = s; }
    int b = d >> 9;
    int r = atomicAdd(&h[b], 1);
    bbuf[bstart[b] + baseo[b] + r] = ((uint)(d & 511) << 17) | (uint)s;
  }
}

// one block (512 thr) per bucket: degrees -> local scan -> offs; rank+scatter in LDS
__global__ void k_build(const uint* __restrict__ bbuf, const int* __restrict__ bstart,
                        int N, int* __restrict__ offs, int* __restrict__ ssrc) {
  __shared__ int deg[512];
  __shared__ int wsum[8];
  int b = blockIdx.x;
  int t = threadIdx.x;
  int lane = t & 63, wid = t >> 6;
  deg[t] = 0;
  __syncthreads();
  int ebeg = bstart[b], eend = bstart[b + 1];
  for (int i = ebeg + t; i < eend; i += 512)
    atomicAdd(&deg[bbuf[i] >> 17], 1);
  __syncthreads();
  int v = deg[t];
  int sv = wave_incl_scan_i(v);
  if (lane == 63) wsum[wid] = sv;
  __syncthreads();
  if (t == 0) {
    int r = 0;
#pragma unroll
    for (int k = 0; k < 8; k++) { int x = wsum[k]; wsum[k] = r; r += x; }
  }
  __syncthreads();
  int excl = wsum[wid] + sv - v;
  int node = (b << 9) + t;
  if (node < N) offs[node] = ebeg + excl;
  __syncthreads();
  deg[t] = excl;                     // becomes local cursor
  __syncthreads();
  for (int i = ebeg + t; i < eend; i += 512) {
    uint rec = bbuf[i];
    int r = atomicAdd(&deg[rec >> 17], 1);
    ssrc[ebeg + r] = (int)(rec & 0x1FFFF);
  }
}

// ---------------- GEMM1: hb1[M,128](bf16) = (nw.x)[M,128] @ W1[128,128] ----------------
__global__ void k_gemm1(const float* __restrict__ A, const float* __restrict__ B,
                        const float* __restrict__ rowscale, ushort* __restrict__ Cb,
                        int M, int K, int Nc) {
  const int BM = 64, BK = 16, BN = 64;
  __shared__ float As[BK][BM + 4];
  __shared__ float Bs[BK][BN];
  const int tid = threadIdx.x;
  const int nth = 256;
  const int tx = tid % (BN / 4);
  const int ty = tid / (BN / 4);
  const int row0 = blockIdx.x * BM;
  const int col0 = blockIdx.y * BN;
  float acc[4][4] = {};
  for (int k0 = 0; k0 < K; k0 += BK) {
    for (int idx = tid; idx < BM * BK; idx += nth) {
      int m = idx >> 4, kk = idx & 15;
      int r = row0 + m;
      float v = 0.f;
      if (r < M) v = A[(size_t)r * K + k0 + kk] * rowscale[r];
      As[kk][m] = v;
    }
    for (int idx = tid; idx < BK * BN; idx += nth) {
      int kk = idx / BN, c = idx % BN;
      Bs[kk][c] = B[(size_t)(k0 + kk) * Nc + col0 + c];
    }
    __syncthreads();
#pragma unroll
    for (int kk = 0; kk < BK; kk++) {
      float4 a4 = *reinterpret_cast<const float4*>(&As[kk][ty * 4]);
      float4 b4 = *reinterpret_cast<const float4*>(&Bs[kk][tx * 4]);
      float av[4] = {a4.x, a4.y, a4.z, a4.w};
      float bv[4] = {b4.x, b4.y, b4.z, b4.w};
#pragma unroll
      for (int i = 0; i < 4; i++)
#pragma unroll
        for (int j = 0; j < 4; j++)
          acc[i][j] += av[i] * bv[j];
    }
    __syncthreads();
  }
#pragma unroll
  for (int i = 0; i < 4; i++) {
    int r = row0 + ty * 4 + i;
    if (r < M) {
      ushort4 o;
      o.x = f2bf(acc[i][0]); o.y = f2bf(acc[i][1]);
      o.z = f2bf(acc[i][2]); o.w = f2bf(acc[i][3]);
      *reinterpret_cast<ushort4*>(&Cb[(size_t)r * Nc + col0 + tx * 4]) = o;
    }
  }
}

// ---------------- GEMM2: hb2[M,32](bf16) = out1b[M,128](bf16) @ W2[128,32] ----------------
__global__ void k_gemm2(const ushort* __restrict__ A, const float* __restrict__ B,
                        ushort* __restrict__ Cb, int M, int K, int Nc) {
  const int BM = 64, BK = 16, BN = 32;
  __shared__ float As[BK][BM + 4];
  __shared__ float Bs[BK][BN];
  const int tid = threadIdx.x;
  const int nth = 128;
  const int tx = tid % (BN / 4);
  const int ty = tid / (BN / 4);
  const int row0 = blockIdx.x * BM;
  float acc[4][4] = {};
  for (int k0 = 0; k0 < K; k0 += BK) {
    for (int idx = tid; idx < BM * BK / 2; idx += nth) {
      int m = idx >> 3;
      int kp = (idx & 7) * 2;
      int r = row0 + m;
      float v0 = 0.f, v1 = 0.f;
      if (r < M) {
        uint p = *reinterpret_cast<const uint*>(A + (size_t)r * K + k0 + kp);
        v0 = bflo(p); v1 = bfhi(p);
      }
      As[kp][m] = v0; As[kp + 1][m] = v1;
    }
    for (int idx = tid; idx < BK * BN; idx += nth) {
      int kk = idx / BN, c = idx % BN;
      Bs[kk][c] = B[(size_t)(k0 + kk) * Nc + c];
    }
    __syncthreads();
#pragma unroll
    for (int kk = 0; kk < BK; kk++) {
      float4 a4 = *reinterpret_cast<const float4*>(&As[kk][ty * 4]);
      float4 b4 = *reinterpret_cast<const float4*>(&Bs[kk][tx * 4]);
      float av[4] = {a4.x, a4.y, a4.z, a4.w};
      float bv[4] = {b4.x, b4.y, b4.z, b4.w};
#pragma unroll
      for (int i = 0; i < 4; i++)
#pragma unroll
        for (int j = 0; j < 4; j++)
          acc[i][j] += av[i] * bv[j];
    }
    __syncthreads();
  }
#pragma unroll
  for (int i = 0; i < 4; i++) {
    int r = row0 + ty * 4 + i;
    if (r < M) {
      ushort4 o;
      o.x = f2bf(acc[i][0]); o.y = f2bf(acc[i][1]);
      o.z = f2bf(acc[i][2]); o.w = f2bf(acc[i][3]);
      *reinterpret_cast<ushort4*>(&Cb[(size_t)r * Nc + tx * 4]) = o;
    }
  }
}

// ---------------- attention scores ----------------
__global__ void k_att1(const ushort* __restrict__ hb, const float* __restrict__ att_s,
                       const float* __restrict__ att_d, float* __restrict__ o_s,
                       float* __restrict__ o_d, int N) {
  int wid = threadIdx.x >> 6, lane = threadIdx.x & 63;
  int n = blockIdx.x * 4 + wid;
  if (n >= N) return;
  int h = lane >> 4;
  int ch = (2 * lane) & 31;
  uint p = *reinterpret_cast<const uint*>(hb + (size_t)n * 128 + 2 * lane);
  float v0 = bflo(p), v1 = bfhi(p);
  float sa = v0 * att_s[h * 32 + ch] + v1 * att_s[h * 32 + ch + 1];
  float da = v0 * att_d[h * 32 + ch] + v1 * att_d[h * 32 + ch + 1];
#pragma unroll
  for (int off = 8; off > 0; off >>= 1) {
    sa += __shfl_xor(sa, off, 16);
    da += __shfl_xor(da, off, 16);
  }
  if ((lane & 15) == 0) { o_s[n * 4 + h] = sa; o_d[n * 4 + h] = da; }
}

__global__ void k_att2(const ushort* __restrict__ hb, const float* __restrict__ att_s,
                       const float* __restrict__ att_d, float* __restrict__ o_s,
                       float* __restrict__ o_d, int N) {
  int grp = threadIdx.x >> 4, l = threadIdx.x & 15;
  int n = blockIdx.x * 16 + grp;
  if (n >= N) return;
  uint p = *reinterpret_cast<const uint*>(hb + (size_t)n * 32 + 2 * l);
  float v0 = bflo(p), v1 = bfhi(p);
  float sa = v0 * att_s[2 * l] + v1 * att_s[2 * l + 1];
  float da = v0 * att_d[2 * l] + v1 * att_d[2 * l + 1];
#pragma unroll
  for (int off = 8; off > 0; off >>= 1) {
    sa += __shfl_xor(sa, off, 16);
    da += __shfl_xor(da, off, 16);
  }
  if (l == 0) { o_s[n] = sa; o_d[n] = da; }
}

// ---------------- layer-1 aggregation: wave per dst, bf16x2 gather, 8-edge unroll ----------------
__global__ void k_aggr1(const int* __restrict__ offs, const int* __restrict__ ssrc,
                        const ushort* __restrict__ hb, const float* __restrict__ asrc,
                        const float* __restrict__ adst, const float* __restrict__ bias,
                        ushort* __restrict__ outb, int N) {
  int wid = threadIdx.x >> 6;
  int lane = threadIdx.x & 63;
  int d = blockIdx.x * 4 + wid;
  if (d >= N) return;
  int h = lane >> 4;
  float ad = adst[d * 4 + h];
  int beg = offs[d], end = offs[d + 1];
  float ax = 0.f, ay = 0.f, ds = 0.f;
  int i = beg;
  for (; i + 8 <= end; i += 8) {
    int s[8]; uint p[8]; float a[8];
#pragma unroll
    for (int j = 0; j < 8; j++) s[j] = ssrc[i + j];
#pragma unroll
    for (int j = 0; j < 8; j++) p[j] = *reinterpret_cast<const uint*>(hb + (size_t)s[j] * 128 + 2 * lane);
#pragma unroll
    for (int j = 0; j < 8; j++) a[j] = asrc[s[j] * 4 + h];
#pragma unroll
    for (int j = 0; j < 8; j++) {
      float e = a[j] + ad; e = e > 0.f ? e : NEG * e;
      float w = __expf(e);
      ax += w * bflo(p[j]); ay += w * bfhi(p[j]); ds += w;
    }
  }
  for (; i < end; i++) {
    int s = ssrc[i];
    uint p = *reinterpret_cast<const uint*>(hb + (size_t)s * 128 + 2 * lane);
    float e = asrc[s * 4 + h] + ad; e = e > 0.f ? e : NEG * e;
    float w = __expf(e);
    ax += w * bflo(p); ay += w * bfhi(p); ds += w;
  }
  float inv = 1.f / ds;
  float rx = ax * inv + bias[2 * lane];
  float ry = ay * inv + bias[2 * lane + 1];
  rx = rx > 0.f ? rx : expm1f(rx);
  ry = ry > 0.f ? ry : expm1f(ry);
  uint pk = (uint)f2bf(rx) | ((uint)f2bf(ry) << 16);
  *reinterpret_cast<uint*>(outb + (size_t)d * 128 + 2 * lane) = pk;
}

// ---------------- layer-2 aggregation: 16 lanes per dst, bf16x2 gather, 8-edge unroll ----------------
__global__ void k_aggr2(const int* __restrict__ offs, const int* __restrict__ ssrc,
                        const ushort* __restrict__ hb, const float* __restrict__ asrc,
                        const float* __restrict__ adst, const float* __restrict__ bias,
                        float* __restrict__ out, int N) {
  int grp = threadIdx.x >> 4;
  int l = threadIdx.x & 15;
  int d = blockIdx.x * 16 + grp;
  if (d >= N) return;
  float ad = adst[d];
  int beg = offs[d], end = offs[d + 1];
  float ax = 0.f, ay = 0.f, ds = 0.f;
  int i = beg;
  for (; i + 8 <= end; i += 8) {
    int s[8]; uint p[8]; float a[8];
#pragma unroll
    for (int j = 0; j < 8; j++) s[j] = ssrc[i + j];
#pragma unroll
    for (int j = 0; j < 8; j++) p[j] = *reinterpret_cast<const uint*>(hb + (size_t)s[j] * 32 + 2 * l);
#pragma unroll
    for (int j = 0; j < 8; j++) a[j] = asrc[s[j]];
#pragma unroll
    for (int j = 0; j < 8; j++) {
      float e = a[j] + ad; e = e > 0.f ? e : NEG * e;
      float w = __expf(e);
      ax += w * bflo(p[j]); ay += w * bfhi(p[j]); ds += w;
    }
  }
  for (; i < end; i++) {
    int s = ssrc[i];
    uint p = *reinterpret_cast<const uint*>(hb + (size_t)s * 32 + 2 * l);
    float e = asrc[s] + ad; e = e > 0.f ? e : NEG * e;
    float w = __expf(e);
    ax += w * bflo(p); ay += w * bfhi(p); ds += w;
  }
  float inv = 1.f / ds;
  float rx = ax * inv + bias[2 * l];
  float ry = ay * inv + bias[2 * l + 1];
  rx = rx > 0.f ? rx : expm1f(rx);
  ry = ry > 0.f ? ry : expm1f(ry);
  float2 o = make_float2(rx, ry);
  *reinterpret_cast<float2*>(&out[(size_t)d * 32 + 2 * l]) = o;
}

// ---------------- pool (mean per graph, batch sorted) + FC ----------------
__global__ void k_pool_fc(const float* __restrict__ h2, const int* __restrict__ batch,
                          const float* __restrict__ fcW, const float* __restrict__ fcb,
                          float* __restrict__ out, int N) {
  int g = blockIdx.x;
  int lo = 0, hi = N;
  while (lo < hi) { int mid = (lo + hi) >> 1; if (batch[mid] < g) lo = mid + 1; else hi = mid; }
  int beg = lo;
  hi = N;
  while (lo < hi) { int mid = (lo + hi) >> 1; if (batch[mid] < g + 1) lo = mid + 1; else hi = mid; }
  int end = lo;
  int t = threadIdx.x, c = t & 31, sub = t >> 5;
  float acc = 0.f;
  for (int n = beg + sub; n < end; n += 8) acc += h2[(size_t)n * 32 + c];
  __shared__ float red[8][32];
  __shared__ float pooled[32];
  red[sub][c] = acc;
  __syncthreads();
  if (sub == 0) {
    float s = 0.f;
#pragma unroll
    for (int i = 0; i < 8; i++) s += red[i][c];
    float cnt = (float)(end - beg);
    pooled[c] = s / fmaxf(cnt, 1.f);
  }
  __syncthreads();
  if (t < 16) {
    float r = fcb[t];
#pragma unroll
    for (int cc = 0; cc < 32; cc++) r += pooled[cc] * fcW[cc * 16 + t];
    out[g * 16 + t] = r;
  }
}

// ---------------- host launch ----------------
extern "C" void kernel_launch(void* const* d_in, const int* in_sizes, int n_in,
                              void* d_out, int out_size, void* d_ws, size_t ws_size,
                              hipStream_t stream) {
  const float* x     = (const float*)d_in[0];
  const int*   ei    = (const int*)d_in[1];
  const int*   batch = (const int*)d_in[2];
  const float* nw    = (const float*)d_in[3];
  const float* W1    = (const float*)d_in[4];
  const float* as1w  = (const float*)d_in[5];
  const float* ad1w  = (const float*)d_in[6];
  const float* b1    = (const float*)d_in[7];
  const float* W2    = (const float*)d_in[8];
  const float* as2w  = (const float*)d_in[9];
  const float* ad2w  = (const float*)d_in[10];
  const float* b2    = (const float*)d_in[11];
  const float* fcW   = (const float*)d_in[12];
  const float* fcb   = (const float*)d_in[13];
  float* out = (float*)d_out;

  const int N = in_sizes[0] / IN_C;
  const int E = in_sizes[1] / 2;
  const int Etot = E + N;
  const int NB = (N + 511) >> 9;

  char* w = (char*)d_ws;
  size_t ofs = 0;
  auto alloc = [&](size_t bytes) {
    char* p = w + ofs;
    ofs += (bytes + 255) & ~(size_t)255;
    return p;
  };
  ushort* hb1    = (ushort*)alloc((size_t)N * 128 * 2);
  ushort* out1b  = (ushort*)alloc((size_t)N * 128 * 2);
  ushort* hb2    = (ushort*)alloc((size_t)N * 32 * 2);
  float*  h2     = (float*)alloc((size_t)N * 32 * 4);
  float*  asrc1  = (float*)alloc((size_t)N * 4 * 4);
  float*  adst1  = (float*)alloc((size_t)N * 4 * 4);
  float*  asrc2  = (float*)alloc((size_t)N * 4);
  float*  adst2  = (float*)alloc((size_t)N * 4);
  int*    bcnt   = (int*)alloc((size_t)(2 * NB) * 4);   // bcnt | bcur (one memset)
  int*    bcur   = bcnt + NB;
  int*    bstart = (int*)alloc((size_t)(NB + 1) * 4);
  int*    offs   = (int*)alloc((size_t)(N + 1) * 4);
  uint*   bbuf   = (uint*)alloc((size_t)Etot * 4);
  int*    ssrc   = (int*)alloc((size_t)Etot * 4);

  hipMemsetAsync(bcnt, 0, (size_t)(2 * NB) * 4, stream);

  // binned CSR build
  const int nbin = (Etot + 4095) / 4096;
  k_bhist<<<nbin, 256, 0, stream>>>(ei, E, Etot, NB, bcnt);
  k_bscan<<<1, 64, 0, stream>>>(bcnt, NB, bstart, Etot, offs, N);
  k_bin<<<nbin, 256, 0, stream>>>(ei, E, Etot, NB, bstart, bcur, bbuf);
  k_build<<<NB, 512, 0, stream>>>(bbuf, bstart, N, offs, ssrc);

  // layer 1
  k_gemm1<<<dim3((N + 63) / 64, 2), 256, 0, stream>>>(x, W1, nw, hb1, N, 128, 128);
  k_att1<<<(N + 3) / 4, 256, 0, stream>>>(hb1, as1w, ad1w, asrc1, adst1, N);
  k_aggr1<<<(N + 3) / 4, 256, 0, stream>>>(offs, ssrc, hb1, asrc1, adst1, b1, out1b, N);

  // layer 2
  k_gemm2<<<dim3((N + 63) / 64, 1), 128, 0, stream>>>(out1b, W2, hb2, N, 128, 32);
  k_att2<<<(N + 15) / 16, 256, 0, stream>>>(hb2, as2w, ad2w, asrc2, adst2, N);
  k_aggr2<<<(N + 15) / 16, 256, 0, stream>>>(offs, ssrc, hb2, asrc2, adst2, b2, h2, N);

  // pool + fc
  k_pool_fc<<<NGRAPH, 256, 0, stream>>>(h2, batch, fcW, fcb, out, N);
}